// Round 8
// baseline (333.797 us; speedup 1.0000x reference)
//
#include <hip/hip_runtime.h>
#include <hip/hip_bf16.h>

// R8: flash = 4 waves x 32q (BM=128), double-buffered gl16 staging, 1 barrier/iter;
//     proj = 128x128 tiles (halve L3 re-read traffic).
// N=8192, D=1024, D_qk=D_v=256, scores *= sqrt(D_qk)=16 (folded into Q).

typedef __attribute__((ext_vector_type(8))) short short8;   // 8 bf16 (MFMA frag)
typedef __attribute__((ext_vector_type(4))) float f32x4;    // MFMA acc frag
typedef __attribute__((ext_vector_type(4))) unsigned int u32x4;

#define MFMA16(a, b, c) __builtin_amdgcn_mfma_f32_16x16x32_bf16((a), (b), (c), 0, 0, 0)

__device__ __forceinline__ unsigned short f2bf(float f) {
    unsigned int u = __builtin_bit_cast(unsigned int, f);
    u += 0x7fffu + ((u >> 16) & 1u);   // RNE
    return (unsigned short)(u >> 16);
}
__device__ __forceinline__ float bf2f(unsigned short h) {
    unsigned int u = ((unsigned int)h) << 16;
    return __builtin_bit_cast(float, u);
}
__device__ __forceinline__ unsigned int cvtpk(float a, float b) {
    unsigned int r;
    asm("v_cvt_pk_bf16_f32 %0, %1, %2" : "=v"(r) : "v"(a), "v"(b));
    return r;
}
__device__ __forceinline__ void gl16(const unsigned short* g, unsigned short* l) {
    __builtin_amdgcn_global_load_lds(
        (const __attribute__((address_space(1))) unsigned int*)g,
        (__attribute__((address_space(3))) unsigned int*)l,
        16, 0, 0);
}

// ---------------- kernel 1a: x fp32 -> xhi + xlo bf16 ----------------
__global__ void convert_x_kernel(const float* __restrict__ x,
                                 unsigned short* __restrict__ xhi,
                                 unsigned short* __restrict__ xlo) {
    int i = blockIdx.x * blockDim.x + threadIdx.x;
    float4 v = reinterpret_cast<const float4*>(x)[i];
    float f[4] = {v.x, v.y, v.z, v.w};
    ushort4 hi, lo;
    unsigned short th[4], tl[4];
#pragma unroll
    for (int j = 0; j < 4; ++j) {
        th[j] = f2bf(f[j]);
        tl[j] = f2bf(f[j] - bf2f(th[j]));
    }
    hi.x = th[0]; hi.y = th[1]; hi.z = th[2]; hi.w = th[3];
    lo.x = tl[0]; lo.y = tl[1]; lo.z = tl[2]; lo.w = tl[3];
    reinterpret_cast<ushort4*>(xhi)[i] = hi;
    reinterpret_cast<ushort4*>(xlo)[i] = lo;
}

// ---------------- kernel 1b: W fp32 -> Whi + Wlo bf16 ----------------
__global__ void convert_w_kernel(const float* __restrict__ Wq,
                                 const float* __restrict__ Wk,
                                 const float* __restrict__ Wv,
                                 unsigned short* __restrict__ Whi,
                                 unsigned short* __restrict__ Wlo) {
    const float* W = (blockIdx.y == 0) ? Wq : (blockIdx.y == 1) ? Wk : Wv;
    int i = blockIdx.x * blockDim.x + threadIdx.x;
    float4 v = reinterpret_cast<const float4*>(W)[i];
    float f[4] = {v.x, v.y, v.z, v.w};
    ushort4 hi, lo;
    unsigned short th[4], tl[4];
#pragma unroll
    for (int j = 0; j < 4; ++j) {
        th[j] = f2bf(f[j]);
        tl[j] = f2bf(f[j] - bf2f(th[j]));
    }
    hi.x = th[0]; hi.y = th[1]; hi.z = th[2]; hi.w = th[3];
    lo.x = tl[0]; lo.y = tl[1]; lo.z = tl[2]; lo.w = tl[3];
    size_t off = (size_t)blockIdx.y * 65536 + i;
    reinterpret_cast<ushort4*>(Whi)[off] = hi;
    reinterpret_cast<ushort4*>(Wlo)[off] = lo;
}

// ---------------- kernel 2: projections, 128x128 tile ----------------
// grid (64, 6): y -> w = y>>1 (Q/K/V), nt = y&1 (col half). 8 waves x 16 rows.
// K-step 64; LDS 64KB -> 2 blocks/CU; same-mtile blocks share an XCD (bid%8).
__launch_bounds__(512, 4)
__global__ void proj_kernel(const unsigned short* __restrict__ xhi,
                            const unsigned short* __restrict__ xlo,
                            const unsigned short* __restrict__ Whi,
                            const unsigned short* __restrict__ Wlo,
                            unsigned short* __restrict__ Qhi, unsigned short* __restrict__ Qlo,
                            unsigned short* __restrict__ Khi, unsigned short* __restrict__ Klo,
                            unsigned short* __restrict__ VT) {
    __shared__ __align__(16) unsigned short xh[128 * 64], xl[128 * 64];
    __shared__ __align__(16) unsigned short wh[128 * 64], wl[128 * 64];
    const int t = threadIdx.x;
    const int mtile = blockIdx.x;
    const int y = blockIdx.y;
    const int w = y >> 1, nt = y & 1;
    const int mb = mtile * 128, nb = nt * 128;
    const unsigned short* WhiW = Whi + (size_t)w * 262144;
    const unsigned short* WloW = Wlo + (size_t)w * 262144;
    const int wid = t >> 6, lane = t & 63, lr = lane & 15, lg = lane >> 4;

    // staging: linear slot s -> content (row = s>>3, c = (s&7)^(row&7))
    int soff[2], ldst[2];
#pragma unroll
    for (int i = 0; i < 2; ++i) {
        int s = t + i * 512;             // 0..1023 slots of 16B
        int row = s >> 3, c = (s & 7) ^ (row & 7);
        soff[i] = row * 1024 + c * 8;
        ldst[i] = s * 8;
    }

    const f32x4 fzero = {0.f, 0.f, 0.f, 0.f};
    f32x4 acc[8];
#pragma unroll
    for (int i = 0; i < 8; ++i) acc[i] = fzero;

    for (int ks = 0; ks < 16; ++ks) {
        const int k0 = ks * 64;
#pragma unroll
        for (int i = 0; i < 2; ++i) {
            gl16(xhi + (size_t)mb * 1024 + k0 + soff[i], xh + ldst[i]);
            gl16(xlo + (size_t)mb * 1024 + k0 + soff[i], xl + ldst[i]);
            gl16(WhiW + (size_t)nb * 1024 + k0 + soff[i], wh + ldst[i]);
            gl16(WloW + (size_t)nb * 1024 + k0 + soff[i], wl + ldst[i]);
        }
        asm volatile("s_waitcnt vmcnt(0)" ::: "memory");
        __syncthreads();
        {
            const int arow = wid * 16 + lr;
            short8 ah[2], al[2];
#pragma unroll
            for (int ko = 0; ko < 2; ++ko) {
                int aidx = arow * 64 + (((ko * 4 + lg) ^ (arow & 7)) << 3);
                ah[ko] = *reinterpret_cast<const short8*>(&xh[aidx]);
                al[ko] = *reinterpret_cast<const short8*>(&xl[aidx]);
            }
#pragma unroll
            for (int ct = 0; ct < 8; ++ct) {
                const int brow = ct * 16 + lr;
#pragma unroll
                for (int ko = 0; ko < 2; ++ko) {
                    int bidx = brow * 64 + (((ko * 4 + lg) ^ (brow & 7)) << 3);
                    short8 bh = *reinterpret_cast<const short8*>(&wh[bidx]);
                    short8 bl = *reinterpret_cast<const short8*>(&wl[bidx]);
                    acc[ct] = MFMA16(ah[ko], bh, acc[ct]);
                    acc[ct] = MFMA16(ah[ko], bl, acc[ct]);
                    acc[ct] = MFMA16(al[ko], bh, acc[ct]);
                }
            }
        }
        __syncthreads();
    }
    const int rbase = mb + wid * 16 + lg * 4;
#pragma unroll
    for (int ct = 0; ct < 8; ++ct) {
        int col = nb + ct * 16 + lr;
        if (w == 2) {   // V stored transposed
            ushort4 v4;
            v4.x = f2bf(acc[ct][0]); v4.y = f2bf(acc[ct][1]);
            v4.z = f2bf(acc[ct][2]); v4.w = f2bf(acc[ct][3]);
            *reinterpret_cast<ushort4*>(VT + (size_t)col * 8192 + rbase) = v4;
        } else {
            unsigned short* Hi = (w == 0) ? Qhi : Khi;
            unsigned short* Lo = (w == 0) ? Qlo : Klo;
            const float scale = (w == 0) ? 16.0f : 1.0f;
#pragma unroll
            for (int j = 0; j < 4; ++j) {
                float v = acc[ct][j] * scale;
                unsigned short h = f2bf(v);
                unsigned short lo = f2bf(v - bf2f(h));
                Hi[(size_t)(rbase + j) * 256 + col] = h;
                Lo[(size_t)(rbase + j) * 256 + col] = lo;
            }
        }
    }
}

// ---------------- kernel 3: flash attention ----------------
// BM=128: 4 waves x 32 q-rows (two 16-row halves). KVBLK=32, KV-split=4,
// grid 256 = 1 block/CU. Double-buffered gl16 staging (96KB), 1 barrier/iter.
__launch_bounds__(256, 1)
__global__ void flash_kernel(const unsigned short* __restrict__ Qhi,
                             const unsigned short* __restrict__ Qlo,
                             const unsigned short* __restrict__ Khi_g,
                             const unsigned short* __restrict__ Klo_g,
                             const unsigned short* __restrict__ VT,
                             unsigned short* __restrict__ Opart,
                             float* __restrict__ Mpart, float* __restrict__ Lpart) {
    __shared__ __align__(16) unsigned short LB[2][24576];  // [Kh|Kl|Vt] x dbuf
    const int t = threadIdx.x;
    const int bid = blockIdx.x;
    const int work = (bid & 7) * 32 + (bid >> 3);   // chunked XCD mapping
    const int split = work >> 6, mtile = work & 63;
    const int mb = mtile * 128;
    const int kv0 = split * 2048;
    const int wid = t >> 6, lane = t & 63, lr = lane & 15, lg = lane >> 4;

    // Q B-frags for two 16-row halves: q = qr0/qr1 (col=lr), k = lg*8+j per ko
    const int qr0 = mb + wid * 32 + lr, qr1 = qr0 + 16;
    short8 qh0[8], ql0[8], qh1[8], ql1[8];
#pragma unroll
    for (int ko = 0; ko < 8; ++ko) {
        int g0 = qr0 * 256 + ko * 32 + lg * 8;
        int g1 = qr1 * 256 + ko * 32 + lg * 8;
        qh0[ko] = *reinterpret_cast<const short8*>(Qhi + g0);
        ql0[ko] = *reinterpret_cast<const short8*>(Qlo + g0);
        qh1[ko] = *reinterpret_cast<const short8*>(Qhi + g1);
        ql1[ko] = *reinterpret_cast<const short8*>(Qlo + g1);
    }

    // staging: 48 16B-units x 64 lanes per iter; 12 units per wave
    int goff[12], ldso[12], isV[12];
    const unsigned short* gbase[12];
#pragma unroll
    for (int i = 0; i < 12; ++i) {
        int u = wid * 12 + i;
        int a = u >> 4, c = u & 15;
        if (a < 2) {    // Khi / Klo chunk: 2 rows x 256
            int krow = c * 2 + (lane >> 5), ksl = lane & 31;
            goff[i] = krow * 256 + ((ksl ^ (krow & 7)) << 3);
            gbase[i] = (a == 0) ? Khi_g : Klo_g;
            isV[i] = 0;
            ldso[i] = a * 8192 + c * 512;
        } else {        // Vt chunk: 16 rows x 32
            int vrow = c * 16 + (lane >> 2), vl = lane & 3;
            goff[i] = vrow * 8192 + ((vl ^ (vrow & 3)) << 3);
            gbase[i] = VT;
            isV[i] = 1;
            ldso[i] = 16384 + c * 512;
        }
    }

    const f32x4 fzero = {0.f, 0.f, 0.f, 0.f};
    f32x4 acc0[16], acc1[16];          // O^T halves: d = dt*16+lg*4+j, q = lr (+16)
#pragma unroll
    for (int i = 0; i < 16; ++i) { acc0[i] = fzero; acc1[i] = fzero; }
    float m0 = -__builtin_inff(), m1 = -__builtin_inff(), lp0 = 0.f, lp1 = 0.f;
    const int xr7 = lr & 7, xr3 = lr & 3;
    const bool lgEven = (lg & 1) == 0;
    const bool lgMid = (lg == 1) || (lg == 2);

    // prologue: stage it=0 into buf0
    {
        const int kvb = kv0, kb = kvb << 8;
#pragma unroll
        for (int i = 0; i < 12; ++i)
            gl16(gbase[i] + (isV[i] ? kvb : kb) + goff[i], &LB[0][0] + ldso[i]);
    }
    int cur = 0;
    for (int it = 0; it < 64; ++it) {
        asm volatile("s_waitcnt vmcnt(0)" ::: "memory");   // own cur-loads done
        __syncthreads();                                   // all waves' loads done
        if (it + 1 < 64) {                                 // stage next (overlaps compute)
            const int kvb = kv0 + (it + 1) * 32, kb = kvb << 8;
#pragma unroll
            for (int i = 0; i < 12; ++i)
                gl16(gbase[i] + (isV[i] ? kvb : kb) + goff[i], &LB[cur ^ 1][0] + ldso[i]);
        }
        const unsigned short* KhP = &LB[cur][0];
        const unsigned short* KlP = KhP + 8192;
        const unsigned short* VtP = KhP + 16384;
        // ---- S^T = K Q^T : lane holds S[kv=lg*4+j (+16)][q] for q-halves ----
        f32x4 s00 = fzero, s10 = fzero, s01 = fzero, s11 = fzero;
        __builtin_amdgcn_s_setprio(1);
#pragma unroll
        for (int ko = 0; ko < 8; ++ko) {
            int sl = (((ko * 4 + lg) ^ xr7) << 3);
            int b0 = lr * 256 + sl;
            int b1 = b0 + 4096;
            short8 bh0 = *reinterpret_cast<const short8*>(&KhP[b0]);
            short8 bl0 = *reinterpret_cast<const short8*>(&KlP[b0]);
            short8 bh1 = *reinterpret_cast<const short8*>(&KhP[b1]);
            short8 bl1 = *reinterpret_cast<const short8*>(&KlP[b1]);
            s00 = MFMA16(bh0, qh0[ko], s00);
            s10 = MFMA16(bh1, qh0[ko], s10);
            s01 = MFMA16(bh0, qh1[ko], s01);
            s11 = MFMA16(bh1, qh1[ko], s11);
            s00 = MFMA16(bl0, qh0[ko], s00);
            s10 = MFMA16(bl1, qh0[ko], s10);
            s01 = MFMA16(bl0, qh1[ko], s01);
            s11 = MFMA16(bl1, qh1[ko], s11);
            s00 = MFMA16(bh0, ql0[ko], s00);
            s10 = MFMA16(bh1, ql0[ko], s10);
            s01 = MFMA16(bh0, ql1[ko], s01);
            s11 = MFMA16(bh1, ql1[ko], s11);
        }
        __builtin_amdgcn_s_setprio(0);
        // ---- softmax per half (row-max: 7 in-lane + 2 shfl) ----
        float mx0 = fmaxf(fmaxf(fmaxf(s00[0], s00[1]), fmaxf(s00[2], s00[3])),
                          fmaxf(fmaxf(s10[0], s10[1]), fmaxf(s10[2], s10[3])));
        float mx1 = fmaxf(fmaxf(fmaxf(s01[0], s01[1]), fmaxf(s01[2], s01[3])),
                          fmaxf(fmaxf(s11[0], s11[1]), fmaxf(s11[2], s11[3])));
        mx0 = fmaxf(mx0, __shfl_xor(mx0, 16));
        mx0 = fmaxf(mx0, __shfl_xor(mx0, 32));
        mx1 = fmaxf(mx1, __shfl_xor(mx1, 16));
        mx1 = fmaxf(mx1, __shfl_xor(mx1, 32));
        if (!__all(fmaxf(mx0 - m0, mx1 - m1) <= 4.0f)) {   // defer-max THR=4
            float nm0 = fmaxf(m0, mx0), nm1 = fmaxf(m1, mx1);
            float sc0 = __expf(m0 - nm0), sc1 = __expf(m1 - nm1);
            lp0 *= sc0; lp1 *= sc1; m0 = nm0; m1 = nm1;
#pragma unroll
            for (int i = 0; i < 16; ++i) { acc0[i] *= sc0; acc1[i] *= sc1; }
        }
        float p00[4], p10[4], p01[4], p11[4];
#pragma unroll
        for (int j = 0; j < 4; ++j) {
            p00[j] = __expf(s00[j] - m0);
            p10[j] = __expf(s10[j] - m0);
            p01[j] = __expf(s01[j] - m1);
            p11[j] = __expf(s11[j] - m1);
        }
        lp0 += (p00[0] + p00[1]) + (p00[2] + p00[3]) + (p10[0] + p10[1]) + (p10[2] + p10[3]);
        lp1 += (p01[0] + p01[1]) + (p01[2] + p01[3]) + (p11[0] + p11[1]) + (p11[2] + p11[3]);
        // ---- in-register P transpose -> PV B-frags (per half) ----
        short8 pa0, pa1;
        {
            unsigned int A0 = cvtpk(p00[0], p00[1]), A1 = cvtpk(p00[2], p00[3]);
            unsigned int B0 = cvtpk(p10[0], p10[1]), B1 = cvtpk(p10[2], p10[3]);
            unsigned int X0 = __shfl_xor(A0, 16), X1 = __shfl_xor(A1, 16);
            unsigned int Y0 = __shfl_xor(B0, 16), Y1 = __shfl_xor(B1, 16);
            unsigned int U0 = lgEven ? A0 : Y0, U1 = lgEven ? A1 : Y1;
            unsigned int U2 = lgEven ? X0 : B0, U3 = lgEven ? X1 : B1;
            unsigned int V0 = __shfl_xor(U0, 48), V1 = __shfl_xor(U1, 48);
            unsigned int V2 = __shfl_xor(U2, 48), V3 = __shfl_xor(U3, 48);
            u32x4 wv;
            wv[0] = lgMid ? V0 : U0; wv[1] = lgMid ? V1 : U1;
            wv[2] = lgMid ? V2 : U2; wv[3] = lgMid ? V3 : U3;
            pa0 = __builtin_bit_cast(short8, wv);
        }
        {
            unsigned int A0 = cvtpk(p01[0], p01[1]), A1 = cvtpk(p01[2], p01[3]);
            unsigned int B0 = cvtpk(p11[0], p11[1]), B1 = cvtpk(p11[2], p11[3]);
            unsigned int X0 = __shfl_xor(A0, 16), X1 = __shfl_xor(A1, 16);
            unsigned int Y0 = __shfl_xor(B0, 16), Y1 = __shfl_xor(B1, 16);
            unsigned int U0 = lgEven ? A0 : Y0, U1 = lgEven ? A1 : Y1;
            unsigned int U2 = lgEven ? X0 : B0, U3 = lgEven ? X1 : B1;
            unsigned int V0 = __shfl_xor(U0, 48), V1 = __shfl_xor(U1, 48);
            unsigned int V2 = __shfl_xor(U2, 48), V3 = __shfl_xor(U3, 48);
            u32x4 wv;
            wv[0] = lgMid ? V0 : U0; wv[1] = lgMid ? V1 : U1;
            wv[2] = lgMid ? V2 : U2; wv[3] = lgMid ? V3 : U3;
            pa1 = __builtin_bit_cast(short8, wv);
        }
        // ---- O^T += V^T P^T : one V-read feeds both halves ----
        __builtin_amdgcn_s_setprio(1);
#pragma unroll
        for (int dt = 0; dt < 16; ++dt) {
            int vidx = (dt * 16 + lr) * 32 + ((lg ^ xr3) << 3);
            short8 bv = *reinterpret_cast<const short8*>(&VtP[vidx]);
            acc0[dt] = MFMA16(bv, pa0, acc0[dt]);
            acc1[dt] = MFMA16(bv, pa1, acc1[dt]);
        }
        __builtin_amdgcn_s_setprio(0);
        cur ^= 1;
    }
    // ---- epilogue: reduce lp across lg; store bf16 O + (m, l), both halves ----
    lp0 += __shfl_xor(lp0, 16); lp0 += __shfl_xor(lp0, 32);
    lp1 += __shfl_xor(lp1, 16); lp1 += __shfl_xor(lp1, 32);
    const int or0 = mb + wid * 32 + lr, or1 = or0 + 16;
    unsigned short* Ob0 = Opart + (size_t)split * 8192 * 256 + (size_t)or0 * 256 + lg * 4;
    unsigned short* Ob1 = Opart + (size_t)split * 8192 * 256 + (size_t)or1 * 256 + lg * 4;
#pragma unroll
    for (int dt = 0; dt < 16; ++dt) {
        *reinterpret_cast<unsigned int*>(Ob0 + dt * 16)     = cvtpk(acc0[dt][0], acc0[dt][1]);
        *reinterpret_cast<unsigned int*>(Ob0 + dt * 16 + 2) = cvtpk(acc0[dt][2], acc0[dt][3]);
        *reinterpret_cast<unsigned int*>(Ob1 + dt * 16)     = cvtpk(acc1[dt][0], acc1[dt][1]);
        *reinterpret_cast<unsigned int*>(Ob1 + dt * 16 + 2) = cvtpk(acc1[dt][2], acc1[dt][3]);
    }
    if (lg == 0) {
        Mpart[split * 8192 + or0] = m0;
        Lpart[split * 8192 + or0] = lp0;
        Mpart[split * 8192 + or1] = m1;
        Lpart[split * 8192 + or1] = lp1;
    }
}

// ---------------- kernel 4: combine 4 KV-split partials ----------------
__global__ void combine_kernel(const unsigned short* __restrict__ Opart,
                               const float* __restrict__ Mpart,
                               const float* __restrict__ Lpart,
                               float* __restrict__ out) {
    const int row = blockIdx.x;
    const int d = threadIdx.x;
    float mm = -__builtin_inff();
#pragma unroll
    for (int s = 0; s < 4; ++s) mm = fmaxf(mm, Mpart[s * 8192 + row]);
    float num = 0.f, den = 0.f;
#pragma unroll
    for (int s = 0; s < 4; ++s) {
        float w = __expf(Mpart[s * 8192 + row] - mm);
        den += w * Lpart[s * 8192 + row];
        num += w * bf2f(Opart[((size_t)s * 8192 + row) * 256 + d]);
    }
    out[(size_t)row * 256 + d] = num / den;
}

extern "C" void kernel_launch(void* const* d_in, const int* in_sizes, int n_in,
                              void* d_out, int out_size, void* d_ws, size_t ws_size,
                              hipStream_t stream) {
    const float* x  = (const float*)d_in[0];
    const float* Wq = (const float*)d_in[1];
    const float* Wk = (const float*)d_in[2];
    const float* Wv = (const float*)d_in[3];
    float* out = (float*)d_out;

    char* ws = (char*)d_ws;
    const size_t SZ_QK = (size_t)8192 * 256 * 2;     // 4 MiB per bf16 array
    unsigned short* Qhi = (unsigned short*)(ws + 0 * SZ_QK);
    unsigned short* Qlo = (unsigned short*)(ws + 1 * SZ_QK);
    unsigned short* Khi = (unsigned short*)(ws + 2 * SZ_QK);
    unsigned short* Klo = (unsigned short*)(ws + 3 * SZ_QK);
    unsigned short* VT  = (unsigned short*)(ws + 4 * SZ_QK);
    float* Mpart = (float*)(ws + 5 * SZ_QK);                    // 128KB
    float* Lpart = (float*)(ws + 5 * SZ_QK + 131072);           // 128KB
    char* uA = ws + 5 * SZ_QK + 262144;              // union region:
    unsigned short* xhi = (unsigned short*)uA;       //   A: xhi+xlo (32MB) + Whi/Wlo (3MB)
    unsigned short* xlo = (unsigned short*)(uA + (size_t)8192 * 1024 * 2);
    unsigned short* Whi = (unsigned short*)(uA + (size_t)2 * 8192 * 1024 * 2);
    unsigned short* Wlo = (unsigned short*)(uA + (size_t)2 * 8192 * 1024 * 2 + 3 * 262144 * 2);
    unsigned short* Opart = (unsigned short*)uA;     //   B: Opart bf16 (16MB)

    convert_x_kernel<<<8192, 256, 0, stream>>>(x, xhi, xlo);
    convert_w_kernel<<<dim3(256, 3), 256, 0, stream>>>(Wq, Wk, Wv, Whi, Wlo);
    proj_kernel<<<dim3(64, 6), 512, 0, stream>>>(xhi, xlo, Whi, Wlo,
                                                 Qhi, Qlo, Khi, Klo, VT);
    flash_kernel<<<256, 256, 0, stream>>>(Qhi, Qlo, Khi, Klo, VT, Opart, Mpart, Lpart);
    combine_kernel<<<8192, 256, 0, stream>>>(Opart, Mpart, Lpart, out);
}

// Round 9
// 271.111 us; speedup vs baseline: 1.2312x; 1.2312x over previous
//
#include <hip/hip_runtime.h>
#include <hip/hip_bf16.h>

// R9: flash = 8 waves x 16q (BM=128), dbuf gl16 staging (96KB), 1 block/CU,
//     2 waves/SIMD; V' pair-packed LDS layout (bank-conflict-free PV reads).
//     proj = 128x128 tiles (kept from R8).
// N=8192, D=1024, D_qk=D_v=256, scores *= sqrt(D_qk)=16 (folded into Q).

typedef __attribute__((ext_vector_type(8))) short short8;   // 8 bf16 (MFMA frag)
typedef __attribute__((ext_vector_type(4))) float f32x4;    // MFMA acc frag
typedef __attribute__((ext_vector_type(4))) unsigned int u32x4;

#define MFMA16(a, b, c) __builtin_amdgcn_mfma_f32_16x16x32_bf16((a), (b), (c), 0, 0, 0)

__device__ __forceinline__ unsigned short f2bf(float f) {
    unsigned int u = __builtin_bit_cast(unsigned int, f);
    u += 0x7fffu + ((u >> 16) & 1u);   // RNE
    return (unsigned short)(u >> 16);
}
__device__ __forceinline__ float bf2f(unsigned short h) {
    unsigned int u = ((unsigned int)h) << 16;
    return __builtin_bit_cast(float, u);
}
__device__ __forceinline__ unsigned int cvtpk(float a, float b) {
    unsigned int r;
    asm("v_cvt_pk_bf16_f32 %0, %1, %2" : "=v"(r) : "v"(a), "v"(b));
    return r;
}
// async global->LDS, 16B/lane; lds dest = wave-uniform base + lane*16 (implicit)
__device__ __forceinline__ void gl16(const unsigned short* g, unsigned short* l) {
    __builtin_amdgcn_global_load_lds(
        (const __attribute__((address_space(1))) unsigned int*)g,
        (__attribute__((address_space(3))) unsigned int*)l,
        16, 0, 0);
}

// ---------------- kernel 1a: x fp32 -> xhi + xlo bf16 ----------------
__global__ void convert_x_kernel(const float* __restrict__ x,
                                 unsigned short* __restrict__ xhi,
                                 unsigned short* __restrict__ xlo) {
    int i = blockIdx.x * blockDim.x + threadIdx.x;
    float4 v = reinterpret_cast<const float4*>(x)[i];
    float f[4] = {v.x, v.y, v.z, v.w};
    ushort4 hi, lo;
    unsigned short th[4], tl[4];
#pragma unroll
    for (int j = 0; j < 4; ++j) {
        th[j] = f2bf(f[j]);
        tl[j] = f2bf(f[j] - bf2f(th[j]));
    }
    hi.x = th[0]; hi.y = th[1]; hi.z = th[2]; hi.w = th[3];
    lo.x = tl[0]; lo.y = tl[1]; lo.z = tl[2]; lo.w = tl[3];
    reinterpret_cast<ushort4*>(xhi)[i] = hi;
    reinterpret_cast<ushort4*>(xlo)[i] = lo;
}

// ---------------- kernel 1b: W fp32 -> Whi + Wlo bf16 ----------------
__global__ void convert_w_kernel(const float* __restrict__ Wq,
                                 const float* __restrict__ Wk,
                                 const float* __restrict__ Wv,
                                 unsigned short* __restrict__ Whi,
                                 unsigned short* __restrict__ Wlo) {
    const float* W = (blockIdx.y == 0) ? Wq : (blockIdx.y == 1) ? Wk : Wv;
    int i = blockIdx.x * blockDim.x + threadIdx.x;
    float4 v = reinterpret_cast<const float4*>(W)[i];
    float f[4] = {v.x, v.y, v.z, v.w};
    ushort4 hi, lo;
    unsigned short th[4], tl[4];
#pragma unroll
    for (int j = 0; j < 4; ++j) {
        th[j] = f2bf(f[j]);
        tl[j] = f2bf(f[j] - bf2f(th[j]));
    }
    hi.x = th[0]; hi.y = th[1]; hi.z = th[2]; hi.w = th[3];
    lo.x = tl[0]; lo.y = tl[1]; lo.z = tl[2]; lo.w = tl[3];
    size_t off = (size_t)blockIdx.y * 65536 + i;
    reinterpret_cast<ushort4*>(Whi)[off] = hi;
    reinterpret_cast<ushort4*>(Wlo)[off] = lo;
}

// ---------------- kernel 2: projections, 128x128 tile (unchanged from R8) ----
__launch_bounds__(512, 4)
__global__ void proj_kernel(const unsigned short* __restrict__ xhi,
                            const unsigned short* __restrict__ xlo,
                            const unsigned short* __restrict__ Whi,
                            const unsigned short* __restrict__ Wlo,
                            unsigned short* __restrict__ Qhi, unsigned short* __restrict__ Qlo,
                            unsigned short* __restrict__ Khi, unsigned short* __restrict__ Klo,
                            unsigned short* __restrict__ VT) {
    __shared__ __align__(16) unsigned short xh[128 * 64], xl[128 * 64];
    __shared__ __align__(16) unsigned short wh[128 * 64], wl[128 * 64];
    const int t = threadIdx.x;
    const int mtile = blockIdx.x;
    const int y = blockIdx.y;
    const int w = y >> 1, nt = y & 1;
    const int mb = mtile * 128, nb = nt * 128;
    const unsigned short* WhiW = Whi + (size_t)w * 262144;
    const unsigned short* WloW = Wlo + (size_t)w * 262144;
    const int wid = t >> 6, lane = t & 63, lr = lane & 15, lg = lane >> 4;

    int soff[2], ldst[2];
#pragma unroll
    for (int i = 0; i < 2; ++i) {
        int s = t + i * 512;
        int row = s >> 3, c = (s & 7) ^ (row & 7);
        soff[i] = row * 1024 + c * 8;
        ldst[i] = s * 8;
    }

    const f32x4 fzero = {0.f, 0.f, 0.f, 0.f};
    f32x4 acc[8];
#pragma unroll
    for (int i = 0; i < 8; ++i) acc[i] = fzero;

    for (int ks = 0; ks < 16; ++ks) {
        const int k0 = ks * 64;
#pragma unroll
        for (int i = 0; i < 2; ++i) {
            gl16(xhi + (size_t)mb * 1024 + k0 + soff[i], xh + ldst[i]);
            gl16(xlo + (size_t)mb * 1024 + k0 + soff[i], xl + ldst[i]);
            gl16(WhiW + (size_t)nb * 1024 + k0 + soff[i], wh + ldst[i]);
            gl16(WloW + (size_t)nb * 1024 + k0 + soff[i], wl + ldst[i]);
        }
        asm volatile("s_waitcnt vmcnt(0)" ::: "memory");
        __syncthreads();
        {
            const int arow = wid * 16 + lr;
            short8 ah[2], al[2];
#pragma unroll
            for (int ko = 0; ko < 2; ++ko) {
                int aidx = arow * 64 + (((ko * 4 + lg) ^ (arow & 7)) << 3);
                ah[ko] = *reinterpret_cast<const short8*>(&xh[aidx]);
                al[ko] = *reinterpret_cast<const short8*>(&xl[aidx]);
            }
#pragma unroll
            for (int ct = 0; ct < 8; ++ct) {
                const int brow = ct * 16 + lr;
#pragma unroll
                for (int ko = 0; ko < 2; ++ko) {
                    int bidx = brow * 64 + (((ko * 4 + lg) ^ (brow & 7)) << 3);
                    short8 bh = *reinterpret_cast<const short8*>(&wh[bidx]);
                    short8 bl = *reinterpret_cast<const short8*>(&wl[bidx]);
                    acc[ct] = MFMA16(ah[ko], bh, acc[ct]);
                    acc[ct] = MFMA16(ah[ko], bl, acc[ct]);
                    acc[ct] = MFMA16(al[ko], bh, acc[ct]);
                }
            }
        }
        __syncthreads();
    }
    const int rbase = mb + wid * 16 + lg * 4;
#pragma unroll
    for (int ct = 0; ct < 8; ++ct) {
        int col = nb + ct * 16 + lr;
        if (w == 2) {   // V stored transposed
            ushort4 v4;
            v4.x = f2bf(acc[ct][0]); v4.y = f2bf(acc[ct][1]);
            v4.z = f2bf(acc[ct][2]); v4.w = f2bf(acc[ct][3]);
            *reinterpret_cast<ushort4*>(VT + (size_t)col * 8192 + rbase) = v4;
        } else {
            unsigned short* Hi = (w == 0) ? Qhi : Khi;
            unsigned short* Lo = (w == 0) ? Qlo : Klo;
            const float scale = (w == 0) ? 16.0f : 1.0f;
#pragma unroll
            for (int j = 0; j < 4; ++j) {
                float v = acc[ct][j] * scale;
                unsigned short h = f2bf(v);
                unsigned short lo = f2bf(v - bf2f(h));
                Hi[(size_t)(rbase + j) * 256 + col] = h;
                Lo[(size_t)(rbase + j) * 256 + col] = lo;
            }
        }
    }
}

// ---------------- kernel 3: flash attention ----------------
// BM=128 = 8 waves x 16q. KVBLK=32, KV-split=4, grid 256 = 1 block/CU,
// 2 waves/SIMD (VGPR ~120 + 64 acc). Dbuf 96KB, 1 barrier/iter.
// LDS per buf: Kh[32][256] | Kl[32][256] | V' pair-packed [128][64].
__launch_bounds__(512, 2)
__global__ void flash_kernel(const unsigned short* __restrict__ Qhi,
                             const unsigned short* __restrict__ Qlo,
                             const unsigned short* __restrict__ Khi_g,
                             const unsigned short* __restrict__ Klo_g,
                             const unsigned short* __restrict__ VT,
                             unsigned short* __restrict__ Opart,
                             float* __restrict__ Mpart, float* __restrict__ Lpart) {
    __shared__ __align__(16) unsigned short LB[2][24576];   // 48KB x dbuf
    const int t = threadIdx.x;
    const int bid = blockIdx.x;
    const int work = (bid & 7) * 32 + (bid >> 3);   // chunked XCD mapping
    const int split = work >> 6, mtile = work & 63;
    const int mb = mtile * 128;
    const int kv0 = split * 2048;
    const int wid = t >> 6, lane = t & 63, lr = lane & 15, lg = lane >> 4;

    // Q B-frags: q = qrow (col=lr), k = lg*8+j per ko
    const int qrow = mb + wid * 16 + lr;
    short8 qh[8], ql[8];
#pragma unroll
    for (int ko = 0; ko < 8; ++ko) {
        int g = qrow * 256 + ko * 32 + lg * 8;
        qh[ko] = *reinterpret_cast<const short8*>(Qhi + g);
        ql[ko] = *reinterpret_cast<const short8*>(Qlo + g);
    }

    // staging: 48 chunks (1KB each) per tile; wave w -> chunks [6w, 6w+6).
    // chunks 0-15: Khi rows; 16-31: Klo rows; 32-47: V' (pair-packed).
    int go[6], lo_[6], isv[6];
    const unsigned short* gb[6];
#pragma unroll
    for (int i = 0; i < 6; ++i) {
        int chunk = wid * 6 + i;
        lo_[i] = chunk * 512;                       // wave-uniform LDS base (u16)
        if (chunk < 32) {
            int cc = chunk & 15;
            int krow = cc * 2 + (lane >> 5);
            go[i] = krow * 256 + (((lane & 31) ^ (krow & 7)) << 3);
            gb[i] = (chunk < 16) ? Khi_g : Klo_g;
            isv[i] = 0;
        } else {
            int cc = chunk - 32;
            // V' lane l -> pair p = cc*8 + (l>>3); d = 2p + ((l&7)>>2);
            // stored col-slot (l&3) holds source block csrc = (l&3)^((l>>3)&3)
            int d = cc * 16 + 2 * (lane >> 3) + ((lane & 7) >> 2);
            int csrc = (lane & 3) ^ ((lane >> 3) & 3);
            go[i] = d * 8192 + csrc * 8;
            gb[i] = VT;
            isv[i] = 1;
        }
    }

    const f32x4 fzero = {0.f, 0.f, 0.f, 0.f};
    f32x4 acc[16];                     // O^T: d = dt*16+lg*4+j, q = lr
#pragma unroll
    for (int i = 0; i < 16; ++i) acc[i] = fzero;
    float m = -__builtin_inff(), lp = 0.f;
    const int xr7 = lr & 7;
    const bool lgEven = (lg & 1) == 0;
    const bool lgMid = (lg == 1) || (lg == 2);

    // prologue: stage tile 0 into buf0
    {
        const int kvb = kv0, kb = kvb << 8;
#pragma unroll
        for (int i = 0; i < 6; ++i)
            gl16(gb[i] + (isv[i] ? kvb : kb) + go[i], &LB[0][0] + lo_[i]);
    }
    int cur = 0;
    for (int it = 0; it < 64; ++it) {
        asm volatile("s_waitcnt vmcnt(0)" ::: "memory");
        __syncthreads();                            // tile `it` resident for all
        if (it + 1 < 64) {                          // stage next (overlaps compute)
            const int kvb = kv0 + (it + 1) * 32, kb = kvb << 8;
#pragma unroll
            for (int i = 0; i < 6; ++i)
                gl16(gb[i] + (isv[i] ? kvb : kb) + go[i], &LB[cur ^ 1][0] + lo_[i]);
        }
        const unsigned short* KhP = &LB[cur][0];
        const unsigned short* KlP = KhP + 8192;
        const unsigned short* VtP = KhP + 16384;
        // ---- S^T = K Q^T : lane holds S[kv=lg*4+j (+16)][q=lr] ----
        f32x4 s0 = fzero, s1 = fzero;
        __builtin_amdgcn_s_setprio(1);
#pragma unroll
        for (int ko = 0; ko < 8; ++ko) {
            int sl = (((ko * 4 + lg) ^ xr7) << 3);
            int b0 = lr * 256 + sl;
            int b1 = b0 + 4096;
            short8 bh0 = *reinterpret_cast<const short8*>(&KhP[b0]);
            short8 bl0 = *reinterpret_cast<const short8*>(&KlP[b0]);
            short8 bh1 = *reinterpret_cast<const short8*>(&KhP[b1]);
            short8 bl1 = *reinterpret_cast<const short8*>(&KlP[b1]);
            s0 = MFMA16(bh0, qh[ko], s0);
            s1 = MFMA16(bh1, qh[ko], s1);
            s0 = MFMA16(bl0, qh[ko], s0);
            s1 = MFMA16(bl1, qh[ko], s1);
            s0 = MFMA16(bh0, ql[ko], s0);
            s1 = MFMA16(bh1, ql[ko], s1);
        }
        __builtin_amdgcn_s_setprio(0);
        // ---- softmax: row-max = 7 in-lane max + 2 shfl ----
        float mx = fmaxf(fmaxf(fmaxf(s0[0], s0[1]), fmaxf(s0[2], s0[3])),
                         fmaxf(fmaxf(s1[0], s1[1]), fmaxf(s1[2], s1[3])));
        mx = fmaxf(mx, __shfl_xor(mx, 16));
        mx = fmaxf(mx, __shfl_xor(mx, 32));
        if (!__all(mx - m <= 4.0f)) {               // defer-max THR=4
            float nm = fmaxf(m, mx);
            float sc = __expf(m - nm);
            lp *= sc;
            m = nm;
#pragma unroll
            for (int i = 0; i < 16; ++i) acc[i] *= sc;
        }
        float p0[4], p1[4];
#pragma unroll
        for (int j = 0; j < 4; ++j) {
            p0[j] = __expf(s0[j] - m);              // bounded by e^4
            p1[j] = __expf(s1[j] - m);
        }
        lp += (p0[0] + p0[1]) + (p0[2] + p0[3]) + (p1[0] + p1[1]) + (p1[2] + p1[3]);
        // ---- in-register P transpose -> PV B-frag ----
        unsigned int A0 = cvtpk(p0[0], p0[1]), A1 = cvtpk(p0[2], p0[3]);
        unsigned int B0 = cvtpk(p1[0], p1[1]), B1 = cvtpk(p1[2], p1[3]);
        unsigned int X0 = __shfl_xor(A0, 16), X1 = __shfl_xor(A1, 16);
        unsigned int Y0 = __shfl_xor(B0, 16), Y1 = __shfl_xor(B1, 16);
        unsigned int U0 = lgEven ? A0 : Y0, U1 = lgEven ? A1 : Y1;
        unsigned int U2 = lgEven ? X0 : B0, U3 = lgEven ? X1 : B1;
        unsigned int V0 = __shfl_xor(U0, 48), V1 = __shfl_xor(U1, 48);
        unsigned int V2 = __shfl_xor(U2, 48), V3 = __shfl_xor(U3, 48);
        u32x4 wv;
        wv[0] = lgMid ? V0 : U0; wv[1] = lgMid ? V1 : U1;
        wv[2] = lgMid ? V2 : U2; wv[3] = lgMid ? V3 : U3;
        short8 pa = __builtin_bit_cast(short8, wv); // P^T[kv=lg*8+j][q=lr]
        // ---- O^T += V^T P^T (V' pair-packed read: 2-way bank = free) ----
        __builtin_amdgcn_s_setprio(1);
#pragma unroll
        for (int dt = 0; dt < 16; ++dt) {
            int vidx = (dt * 8 + (lr >> 1)) * 64 + ((lr & 1) << 5)
                     + ((lg ^ ((lr >> 1) & 3)) << 3);
            short8 bv = *reinterpret_cast<const short8*>(&VtP[vidx]);
            acc[dt] = MFMA16(bv, pa, acc[dt]);
        }
        __builtin_amdgcn_s_setprio(0);
        cur ^= 1;
    }
    // ---- epilogue ----
    lp += __shfl_xor(lp, 16);
    lp += __shfl_xor(lp, 32);
    const int orow = mb + wid * 16 + lr;
    unsigned short* Ob = Opart + (size_t)split * 8192 * 256 + (size_t)orow * 256 + lg * 4;
#pragma unroll
    for (int dt = 0; dt < 16; ++dt) {
        *reinterpret_cast<unsigned int*>(Ob + dt * 16)     = cvtpk(acc[dt][0], acc[dt][1]);
        *reinterpret_cast<unsigned int*>(Ob + dt * 16 + 2) = cvtpk(acc[dt][2], acc[dt][3]);
    }
    if (lg == 0) {
        Mpart[split * 8192 + orow] = m;
        Lpart[split * 8192 + orow] = lp;
    }
}

// ---------------- kernel 4: combine 4 KV-split partials ----------------
__global__ void combine_kernel(const unsigned short* __restrict__ Opart,
                               const float* __restrict__ Mpart,
                               const float* __restrict__ Lpart,
                               float* __restrict__ out) {
    const int row = blockIdx.x;
    const int d = threadIdx.x;
    float mm = -__builtin_inff();
#pragma unroll
    for (int s = 0; s < 4; ++s) mm = fmaxf(mm, Mpart[s * 8192 + row]);
    float num = 0.f, den = 0.f;
#pragma unroll
    for (int s = 0; s < 4; ++s) {
        float w = __expf(Mpart[s * 8192 + row] - mm);
        den += w * Lpart[s * 8192 + row];
        num += w * bf2f(Opart[((size_t)s * 8192 + row) * 256 + d]);
    }
    out[(size_t)row * 256 + d] = num / den;
}

extern "C" void kernel_launch(void* const* d_in, const int* in_sizes, int n_in,
                              void* d_out, int out_size, void* d_ws, size_t ws_size,
                              hipStream_t stream) {
    const float* x  = (const float*)d_in[0];
    const float* Wq = (const float*)d_in[1];
    const float* Wk = (const float*)d_in[2];
    const float* Wv = (const float*)d_in[3];
    float* out = (float*)d_out;

    char* ws = (char*)d_ws;
    const size_t SZ_QK = (size_t)8192 * 256 * 2;     // 4 MiB per bf16 array
    unsigned short* Qhi = (unsigned short*)(ws + 0 * SZ_QK);
    unsigned short* Qlo = (unsigned short*)(ws + 1 * SZ_QK);
    unsigned short* Khi = (unsigned short*)(ws + 2 * SZ_QK);
    unsigned short* Klo = (unsigned short*)(ws + 3 * SZ_QK);
    unsigned short* VT  = (unsigned short*)(ws + 4 * SZ_QK);
    float* Mpart = (float*)(ws + 5 * SZ_QK);                    // 128KB
    float* Lpart = (float*)(ws + 5 * SZ_QK + 131072);           // 128KB
    char* uA = ws + 5 * SZ_QK + 262144;              // union region:
    unsigned short* xhi = (unsigned short*)uA;       //   A: xhi+xlo (32MB) + Whi/Wlo (3MB)
    unsigned short* xlo = (unsigned short*)(uA + (size_t)8192 * 1024 * 2);
    unsigned short* Whi = (unsigned short*)(uA + (size_t)2 * 8192 * 1024 * 2);
    unsigned short* Wlo = (unsigned short*)(uA + (size_t)2 * 8192 * 1024 * 2 + 3 * 262144 * 2);
    unsigned short* Opart = (unsigned short*)uA;     //   B: Opart bf16 (16MB)

    convert_x_kernel<<<8192, 256, 0, stream>>>(x, xhi, xlo);
    convert_w_kernel<<<dim3(256, 3), 256, 0, stream>>>(Wq, Wk, Wv, Whi, Wlo);
    proj_kernel<<<dim3(64, 6), 512, 0, stream>>>(xhi, xlo, Whi, Wlo,
                                                 Qhi, Qlo, Khi, Klo, VT);
    flash_kernel<<<256, 512, 0, stream>>>(Qhi, Qlo, Khi, Klo, VT, Opart, Mpart, Lpart);
    combine_kernel<<<8192, 256, 0, stream>>>(Opart, Mpart, Lpart, out);
}